// Round 8
// baseline (151.138 us; speedup 1.0000x reference)
//
#include <hip/hip_runtime.h>

// Causal GQA attention prefill, fp32 in/out, MFMA 32x32x16 bf16 compute.
// S=2048, H=32, KVH=8 (rep=4), D=128.
// Round 13 on round 12 (69-70 us; conflicts=0 and addr-VALU removed but time
// FLAT -> neither was binding. 2 waves/SIMD phase-locked => MFMA and
// VALU/trans phases serialize; 44% idle = in-wave dependency stall):
//   T15 lag-1 PV pipeline: window it = QK(it) [MFMA] ; PV(it-1) [MFMA,
//   independent] ; softmax(it) [VALU/trans overlapped under PV by the
//   scheduler]. P fragments (af*, 16 VGPR) carried one window.
//   - V TRIPLE-buffered (tile t -> buf t%3): ISSUE(it+2) rewrites exactly
//     the buffer PV(it-1) just drained ((it+2) == (it-1) mod 3).
//   - K stays double-buffered. LDS = 64K + 96K = 163840 B (full 160 KiB);
//     Sl aliased into dead V region during epilogue.
//   - st zero-init via persistent zero-C MFMA operand (saves 32 movs/iter).
// Kept from round 12: slice-major workspaces (zero conflicts, immediate-
// offset ds_reads), unnormalized softmax (exp2 direct), ones-MFMA row-sum,
// gload_lds width-16 staging, counted-vmcnt depth-2, persistent blocks
// (grid=256, q-tiles px then 15-px = 17 BK=128 iters), XCD-exact h map.

#define SEQ   2048
#define NH    32
#define NKVH  8
#define HD    128
#define BQ    128
#define BK    128    // staged keys per iteration (2 wave-groups x 64)
#define KSS   136    // fallback kernel K stride
#define VTSF  72     // fallback kernel V stride
#define PSS   72     // fallback ps stride
#define SCALE 0.08838834764831845f
#define QS    (0.08838834764831845f * 1.4426950408889634f)   // SCALE * log2(e)

#define TILE_SH 16384                        // shorts per 128x128 bf16 tile
#define KB_ELEMS (SEQ * NKVH * HD)           // 2,097,152 ushorts
#define WS_NEED  (2u * KB_ELEMS * 2u)        // kws + vws, bytes

typedef __attribute__((ext_vector_type(8)))  short short8;
typedef __attribute__((ext_vector_type(16))) float float16;
typedef __attribute__((ext_vector_type(2)))  unsigned int uint2v;

__device__ __forceinline__ unsigned short f2bf(float f) {
    union { float f; unsigned int i; } x; x.f = f;
    unsigned int r = x.i + 0x7fffu + ((x.i >> 16) & 1u);   // RNE
    return (unsigned short)(r >> 16);
}
__device__ __forceinline__ unsigned int f2bf2(float lo, float hi) {
    return (unsigned int)f2bf(lo) | ((unsigned int)f2bf(hi) << 16);
}
__device__ __forceinline__ unsigned int cvt_pk_bf16(float lo, float hi) {
    unsigned int r;
    asm("v_cvt_pk_bf16_f32 %0, %1, %2" : "=v"(r) : "v"(lo), "v"(hi));
    return r;
}

// direct global->LDS copy, 16 B per lane; LDS dest is wave-uniform base,
// HW adds lane*16; global src is per-lane.
__device__ __forceinline__ void gload_lds16(const unsigned short* g, unsigned short* l) {
    __builtin_amdgcn_global_load_lds(
        (const __attribute__((address_space(1))) void*)g,
        (__attribute__((address_space(3))) void*)l, 16, 0, 0);
}

#if __has_builtin(__builtin_amdgcn_permlane32_swap)
#define PLSWAP(a, b, xout, yout) do { \
    uint2v r_ = __builtin_amdgcn_permlane32_swap((a), (b), false, false); \
    (xout) = r_.x; (yout) = r_.y; } while (0)
#else
#define PLSWAP(a, b, xout, yout) do { \
    unsigned int a_ = (a), b_ = (b); \
    asm volatile("s_nop 1\n\tv_permlane32_swap_b32 %0, %1" : "+v"(a_), "+v"(b_)); \
    (xout) = a_; (yout) = b_; } while (0)
#endif

#define MAKE_AF(dst, sv, b) do { \
    const unsigned int p0_ = cvt_pk_bf16(sv[(b) + 0], sv[(b) + 1]); \
    const unsigned int p1_ = cvt_pk_bf16(sv[(b) + 2], sv[(b) + 3]); \
    const unsigned int p2_ = cvt_pk_bf16(sv[(b) + 4], sv[(b) + 5]); \
    const unsigned int p3_ = cvt_pk_bf16(sv[(b) + 6], sv[(b) + 7]); \
    unsigned int w0_, w1_, w2_, w3_; \
    PLSWAP(p0_, p2_, w0_, w2_); \
    PLSWAP(p1_, p3_, w1_, w3_); \
    union { short8 v; unsigned int u[4]; } uu_; \
    uu_.u[0] = w0_; uu_.u[1] = w1_; uu_.u[2] = w2_; uu_.u[3] = w3_; \
    (dst) = uu_.v; } while (0)

// ---- prep: build slice-major bf16 workspaces ----
// kws[kvh][tile16][gl16][row128] : 8-short unit (gl*128+row)*8 holds
//   K[tile*128+row][d = gl*8 .. gl*8+8) as bf16.
// vws[kvh][tile16][gl16][d128]   : unit (gl*128+d)*8 holds
//   V[key = tile*128+gl*8+e][d], e=0..7 (V^T key-slice at dim d).
__global__ __launch_bounds__(256)
void cvt_kv3(const float* __restrict__ k, const float* __restrict__ v,
             unsigned short* __restrict__ kws, unsigned short* __restrict__ vws)
{
    __shared__ unsigned short tl[128 * 144];
    const int t = threadIdx.x;
    if (blockIdx.x < 128) {                  // ---- K slice-major ----
        const int bid = blockIdx.x;
        const int kvh = bid >> 4, tile = bid & 15;
        unsigned short* dst = kws + (size_t)bid * TILE_SH;
        #pragma unroll
        for (int r = 0; r < 8; ++r) {
            const int gid = r * 256 + t;     // 0..2047
            const int gl = gid >> 7, row = gid & 127;
            const float* src =
                k + ((size_t)(tile * 128 + row) * NKVH + kvh) * HD + gl * 8;
            const float4 a = *(const float4*)(src);
            const float4 b = *(const float4*)(src + 4);
            uint4 o;
            o.x = f2bf2(a.x, a.y); o.y = f2bf2(a.z, a.w);
            o.z = f2bf2(b.x, b.y); o.w = f2bf2(b.z, b.w);
            *(uint4*)(dst + (size_t)gid * 8) = o;
        }
        return;
    }
    // ---- V transpose + slice-major ----
    const int bid = blockIdx.x - 128;
    const int kvh = bid >> 4, tile = bid & 15;
    const int dp  = (t & 63) * 2;
    const int k0q = t >> 6;
    #pragma unroll
    for (int r = 0; r < 32; ++r) {
        const int key = k0q + r * 4;         // 0..127
        const float2 a =
            *(const float2*)(v + ((size_t)(tile * 128 + key) * NKVH + kvh) * HD + dp);
        tl[dp * 144 + key]       = f2bf(a.x);
        tl[(dp + 1) * 144 + key] = f2bf(a.y);
    }
    __syncthreads();
    unsigned short* dst = vws + (size_t)bid * TILE_SH;
    #pragma unroll
    for (int r = 0; r < 8; ++r) {
        const int gid = r * 256 + t;
        const int gl = gid >> 7, d = gid & 127;
        *(uint4*)(dst + (size_t)gid * 8) = *(const uint4*)&tl[d * 144 + gl * 8];
    }
}

// ---- main: persistent 512-thread blocks, 2 q-tiles each, 17 iters total ----
__global__ __launch_bounds__(512, 1)
void attn_fwd9(const float* __restrict__ q,
               const unsigned short* __restrict__ kws,
               const unsigned short* __restrict__ vws,
               float* __restrict__ out)
{
    // K double-buffer (2x32KB) + V triple-buffer (3x32KB) = 163840 B (max).
    // epilogue: obuf (64KB) aliases K region; Sl aliases V region (dead).
    __shared__ __align__(16) unsigned char smem[163840];
    unsigned short* const ks0 = (unsigned short*)smem;
    unsigned short* const ks1 = (unsigned short*)(smem + 32768);
    unsigned short* const vb0 = (unsigned short*)(smem + 65536);
    unsigned short* const vb1 = (unsigned short*)(smem + 98304);
    unsigned short* const vb2 = (unsigned short*)(smem + 131072);
    float*          const obuf = (float*)smem;                 // 64 KB
    float*          const Slp  = (float*)(smem + 65536);       // 1 KB, epilogue only

    const int t    = threadIdx.x;          // 0..511
    const int w    = t >> 6;               // wave 0..7
    const int lane = t & 63;
    const int ln   = lane & 31;
    const int half = lane >> 5;
    const int g    = w >> 2;               // key-group 0/1
    const int w3   = w & 3;                // q-subtile 0..3

    // XCD-exact mapping: blocks with bid%8==x share kvh==x on XCD x.
    const int bid = blockIdx.x;            // 0..255
    const int h   = (bid & 7) * 4 + ((bid >> 3) & 3);
    const int px  = bid >> 5;              // 0..7
    const int kvh = h >> 2;

    // slice-major per-lane LDS read bases (shorts); all reads are
    // base + compile-time immediate offsets.
    const int kofs = half * 1024 + (g * 64 + ln) * 8;   // K: [gl][row]
    const int vofs = (g * 8 + half) * 1024 + ln * 8;    // V: [gl][d]

    // linear staging sources: thread t covers bytes t*16 + j*8192 of tile.
    const unsigned short* const kgp = kws + (size_t)(kvh * 16) * TILE_SH + t * 8;
    const unsigned short* const vgp = vws + (size_t)(kvh * 16) * TILE_SH + t * 8;
    const int wofs = w * 512;              // wave-uniform LDS offset (shorts)

    // all-ones bf16 B fragment for the l row-sum MFMA
    short8 onesv;
    {
        union { short8 v; unsigned int u[4]; } uo;
        uo.u[0] = uo.u[1] = uo.u[2] = uo.u[3] = 0x3F803F80u;
        onesv = uo.v;
    }

#define ISSUE(tix, kb_, vb_) do { \
    const unsigned short* kg_ = kgp + (size_t)(tix) * TILE_SH; \
    const unsigned short* vg_ = vgp + (size_t)(tix) * TILE_SH; \
    gload_lds16(kg_,         (kb_) + wofs); \
    gload_lds16(kg_ +  4096, (kb_) + wofs + 4096); \
    gload_lds16(kg_ +  8192, (kb_) + wofs + 8192); \
    gload_lds16(kg_ + 12288, (kb_) + wofs + 12288); \
    gload_lds16(vg_,         (vb_) + wofs); \
    gload_lds16(vg_ +  4096, (vb_) + wofs + 4096); \
    gload_lds16(vg_ +  8192, (vb_) + wofs + 8192); \
    gload_lds16(vg_ + 12288, (vb_) + wofs + 12288); \
} while (0)

#define PV4(base) do { \
    const unsigned short* vp_ = (base) + vofs; \
    _Pragma("unroll") \
    for (int kc = 0; kc < 4; ++kc) { \
        const short8 pa = (kc == 0) ? afp0 : (kc == 1) ? afp1 : (kc == 2) ? afp2 : afp3; \
        const short8 bv0 = *(const short8*)&vp_[kc * 2048]; \
        const short8 bv1 = *(const short8*)&vp_[kc * 2048 + 256]; \
        const short8 bv2 = *(const short8*)&vp_[kc * 2048 + 512]; \
        const short8 bv3 = *(const short8*)&vp_[kc * 2048 + 768]; \
        o0 = __builtin_amdgcn_mfma_f32_32x32x16_bf16(pa, bv0, o0, 0, 0, 0); \
        o1 = __builtin_amdgcn_mfma_f32_32x32x16_bf16(pa, bv1, o1, 0, 0, 0); \
        o2 = __builtin_amdgcn_mfma_f32_32x32x16_bf16(pa, bv2, o2, 0, 0, 0); \
        o3 = __builtin_amdgcn_mfma_f32_32x32x16_bf16(pa, bv3, o3, 0, 0, 0); \
        lacc = __builtin_amdgcn_mfma_f32_32x32x16_bf16(pa, onesv, lacc, 0, 0, 0); \
    } \
} while (0)

    for (int ph = 0; ph < 2; ++ph) {
        const int bx    = ph ? (15 - px) : px;
        const int q0    = bx * BQ;
        const int wq0   = q0 + w3 * 32;
        const int qrow  = wq0 + ln;
        const int wqmax = wq0 + 31;
        const int nit   = bx + 1;          // BK=128 iterations

        // ---- Q fragments, pre-scaled by SCALE*log2(e) ----
        short8 qf[8];
        {
            const float* qr = q + ((size_t)qrow * NH + h) * HD;
            #pragma unroll
            for (int k0 = 0; k0 < 8; ++k0) {
                const float* p4 = qr + k0 * 16 + half * 8;
                const float4 a = *(const float4*)(p4);
                const float4 b = *(const float4*)(p4 + 4);
                union { short8 v; unsigned int u[4]; } uu;
                uu.u[0] = f2bf2(a.x * QS, a.y * QS);
                uu.u[1] = f2bf2(a.z * QS, a.w * QS);
                uu.u[2] = f2bf2(b.x * QS, b.y * QS);
                uu.u[3] = f2bf2(b.z * QS, b.w * QS);
                qf[k0] = uu.v;
            }
        }

        float16 o0, o1, o2, o3, lacc, z16;
        #pragma unroll
        for (int i = 0; i < 16; ++i) {
            o0[i] = 0.f; o1[i] = 0.f; o2[i] = 0.f; o3[i] = 0.f;
            lacc[i] = 0.f; z16[i] = 0.f;
        }

        short8 afp0 = onesv, afp1 = onesv, afp2 = onesv, afp3 = onesv;
        bool prevAct = false;

        // V buffer rotation: tile t lives in buf t%3.
        unsigned short* vA = vb0;          // holds tile it   (current)
        unsigned short* vB = vb1;          // holds tile it+1 (next)
        unsigned short* vC = vb2;          // holds tile it-1 (prev / write target)

        ISSUE(0, ks0, vb0);
        if (nit > 1) ISSUE(1, ks1, vb1);

        for (int it = 0; it < nit; ++it) {
            const int cur = it & 1;
            const unsigned short* ksc = (cur ? ks1 : ks0) + kofs;

            // tile it complete; tile it+1's 8 loads may stay in flight
            if (it + 1 < nit) asm volatile("s_waitcnt vmcnt(8)" ::: "memory");
            else              asm volatile("s_waitcnt vmcnt(0)" ::: "memory");
            __builtin_amdgcn_s_barrier();
            __builtin_amdgcn_sched_barrier(0);

            const int j0g = it * BK + g * 64;   // this wave-group's key base
            const bool curAct = (j0g <= wqmax);

            float16 st0, st1;
            if (curAct) {
                // ---- S^T = K Q^T (pre-scaled, log2 domain) ----
                __builtin_amdgcn_s_setprio(1);
                {
                    const short8 a0 = *(const short8*)&ksc[0];
                    const short8 a1 = *(const short8*)&ksc[256];
                    st0 = __builtin_amdgcn_mfma_f32_32x32x16_bf16(a0, qf[0], z16, 0, 0, 0);
                    st1 = __builtin_amdgcn_mfma_f32_32x32x16_bf16(a1, qf[0], z16, 0, 0, 0);
                }
                #pragma unroll
                for (int k0 = 1; k0 < 8; ++k0) {
                    const short8 a0 = *(const short8*)&ksc[k0 * 2048];
                    const short8 a1 = *(const short8*)&ksc[k0 * 2048 + 256];
                    st0 = __builtin_amdgcn_mfma_f32_32x32x16_bf16(a0, qf[k0], st0, 0, 0, 0);
                    st1 = __builtin_amdgcn_mfma_f32_32x32x16_bf16(a1, qf[k0], st1, 0, 0, 0);
                }
                __builtin_amdgcn_s_setprio(0);
            }

            // ---- PV of tile it-1 (MFMA) -- independent of softmax(it) below;
            // the scheduler hides exp2/cvt under these 20 MFMAs.
            if (prevAct) {
                __builtin_amdgcn_s_setprio(1);
                PV4(vC);
                __builtin_amdgcn_s_setprio(0);
            }

            if (curAct) {
                // ---- causal mask (diagonal tiles only) ----
                if ((j0g + 63) > wq0) {
                    #pragma unroll
                    for (int r = 0; r < 16; ++r) {
                        const int kl = (r & 3) + 8 * (r >> 2) + 4 * half;
                        if (j0g + kl > qrow)      st0[r] = -1e30f;
                        if (j0g + 32 + kl > qrow) st1[r] = -1e30f;
                    }
                }
                // ---- unnormalized P = exp2(st); pack to bf16 fragments ----
                #pragma unroll
                for (int r = 0; r < 16; ++r) st0[r] = exp2f(st0[r]);
                MAKE_AF(afp0, st0, 0);
                MAKE_AF(afp1, st0, 8);
                #pragma unroll
                for (int r = 0; r < 16; ++r) st1[r] = exp2f(st1[r]);
                MAKE_AF(afp2, st1, 0);
                MAKE_AF(afp3, st1, 8);
            }

            // all LDS reads of this window's buffers complete before restage
            asm volatile("s_waitcnt lgkmcnt(0)" ::: "memory");
            __builtin_amdgcn_s_barrier();
            __builtin_amdgcn_sched_barrier(0);
            // K(it+2) -> ks[cur] (just-read K buffer); V(it+2) -> vC
            // ((it+2) == (it-1) mod 3: the buffer PV just drained).
            if (it + 2 < nit) ISSUE(it + 2, cur ? ks1 : ks0, vC);

            // rotate V buffers: prev <- cur, cur <- next, next <- old prev
            unsigned short* tmp = vC; vC = vA; vA = vB; vB = tmp;
            prevAct = curAct;
        }

        // ---- drain: PV of the final tile (vC holds tile nit-1 after rotation)
        if (prevAct) PV4(vC);

        // ---- epilogue: merge key-group partials, write out ----
        __syncthreads();                   // all compute + LDS reads done
        if (ln == 0) {
            #pragma unroll
            for (int r = 0; r < 16; ++r)
                Slp[((g * 4 + w3) * 32) + ((r & 3) + 8 * (r >> 2) + 4 * half)] = lacc[r];
        }
        if (g == 1) {
            #pragma unroll
            for (int r = 0; r < 16; ++r) {
                const int rl = (r & 3) + 8 * (r >> 2) + 4 * half;
                float* ob = &obuf[(size_t)(w3 * 32 + rl) * 128];
                ob[ln]      = o0[r];
                ob[32 + ln] = o1[r];
                ob[64 + ln] = o2[r];
                ob[96 + ln] = o3[r];
            }
        }
        __syncthreads();
        if (g == 0) {
            #pragma unroll
            for (int r = 0; r < 16; ++r) {
                const int rl = (r & 3) + 8 * (r >> 2) + 4 * half;
                const float inv = 1.f / (Slp[(w3 * 32) + rl] + Slp[((4 + w3) * 32) + rl]);
                const float* ob = &obuf[(size_t)(w3 * 32 + rl) * 128];
                float* orow = out + ((size_t)(wq0 + rl) * NH + h) * HD;
                orow[ln]      = (o0[r] + ob[ln])      * inv;
                orow[32 + ln] = (o1[r] + ob[32 + ln]) * inv;
                orow[64 + ln] = (o2[r] + ob[64 + ln]) * inv;
                orow[96 + ln] = (o3[r] + ob[96 + ln]) * inv;
            }
        }
        __syncthreads();   // obuf/Sl reads done before next phase restages pool
    }
#undef PV4
#undef ISSUE
}

// ---- fallback (round-4 kernel, no workspace needed) ----
__global__ __launch_bounds__(256, 2)
void attn_fwd_fb(const float* __restrict__ q,
                 const float* __restrict__ k,
                 const float* __restrict__ v,
                 float* __restrict__ out)
{
    __shared__ unsigned short ks[64 * KSS];
    __shared__ unsigned short vt[HD * VTSF];
    __shared__ unsigned short ps[4][32 * PSS];
    __shared__ float          alf[4][32];

    const int t    = threadIdx.x;
    const int w    = t >> 6;
    const int lane = t & 63;
    const int ln   = lane & 31;
    const int half = lane >> 5;
    const int h    = blockIdx.y;
    const int kvh  = h >> 2;
    const int q0   = blockIdx.x * BQ;
    const int wq0  = q0 + w * 32;
    const int qrow = wq0 + ln;

    short8 qf[8];
    {
        const float* qr = q + ((size_t)qrow * NH + h) * HD;
        #pragma unroll
        for (int k0 = 0; k0 < 8; ++k0) {
            const float* p4 = qr + k0 * 16 + half * 8;
            const float4 a = *(const float4*)(p4);
            const float4 b = *(const float4*)(p4 + 4);
            union { short8 v; unsigned int u[4]; } uu;
            uu.u[0] = f2bf2(a.x, a.y);
            uu.u[1] = f2bf2(a.z, a.w);
            uu.u[2] = f2bf2(b.x, b.y);
            uu.u[3] = f2bf2(b.z, b.w);
            qf[k0] = uu.v;
        }
    }

    float16 o0, o1, o2, o3;
    #pragma unroll
    for (int i = 0; i < 16; ++i) { o0[i] = 0.f; o1[i] = 0.f; o2[i] = 0.f; o3[i] = 0.f; }
    float m_run = -1e30f, l_run = 0.f;
    const int ntiles = (q0 + BQ) / 64;
    const int wqmax  = wq0 + 31;

    for (int it = 0; it < ntiles; ++it) {
        const int j0 = it * 64;
        __syncthreads();
        {
            const int key = t >> 2;
            const int db  = (t & 3) * 4;
            const float* kr = k + ((size_t)(j0 + key) * NKVH + kvh) * HD;
            #pragma unroll
            for (int r2 = 0; r2 < 8; ++r2) {
                const int d = db + r2 * 16;
                const float4 a = *(const float4*)(kr + d);
                *(unsigned int*)&ks[key * KSS + d]     = f2bf2(a.x, a.y);
                *(unsigned int*)&ks[key * KSS + d + 2] = f2bf2(a.z, a.w);
            }
        }
        {
            const int kp = (t & 31) * 2;
            const int db = (t >> 5) * 4;
            const float* vr0 = v + ((size_t)(j0 + kp) * NKVH + kvh) * HD;
            const float* vr1 = vr0 + NKVH * HD;
            #pragma unroll
            for (int r2 = 0; r2 < 4; ++r2) {
                const int d = db + r2 * 32;
                const float4 a = *(const float4*)(vr0 + d);
                const float4 b = *(const float4*)(vr1 + d);
                *(unsigned int*)&vt[(d + 0) * VTSF + kp] = f2bf2(a.x, b.x);
                *(unsigned int*)&vt[(d + 1) * VTSF + kp] = f2bf2(a.y, b.y);
                *(unsigned int*)&vt[(d + 2) * VTSF + kp] = f2bf2(a.z, b.z);
                *(unsigned int*)&vt[(d + 3) * VTSF + kp] = f2bf2(a.w, b.w);
            }
        }
        __syncthreads();
        if (j0 > wqmax) continue;

        float16 st0, st1;
        #pragma unroll
        for (int i = 0; i < 16; ++i) { st0[i] = 0.f; st1[i] = 0.f; }
        #pragma unroll
        for (int k0 = 0; k0 < 8; ++k0) {
            const short8 a0 = *(const short8*)&ks[ln * KSS + k0 * 16 + half * 8];
            const short8 a1 = *(const short8*)&ks[(32 + ln) * KSS + k0 * 16 + half * 8];
            st0 = __builtin_amdgcn_mfma_f32_32x32x16_bf16(a0, qf[k0], st0, 0, 0, 0);
            st1 = __builtin_amdgcn_mfma_f32_32x32x16_bf16(a1, qf[k0], st1, 0, 0, 0);
        }
        const bool need_mask = (j0 + 63) > wq0;
        float mt = -1e30f;
        #pragma unroll
        for (int r = 0; r < 16; ++r) {
            const int kl = (r & 3) + 8 * (r >> 2) + 4 * half;
            float a0 = st0[r] * SCALE;
            float a1 = st1[r] * SCALE;
            if (need_mask) {
                if (j0 + kl > qrow)      a0 = -1e30f;
                if (j0 + 32 + kl > qrow) a1 = -1e30f;
            }
            st0[r] = a0; st1[r] = a1;
            mt = fmaxf(mt, fmaxf(a0, a1));
        }
        mt = fmaxf(mt, __shfl_xor(mt, 32, 64));
        const float mn = fmaxf(m_run, mt);
        float sm = 0.f;
        #pragma unroll
        for (int r = 0; r < 16; ++r) {
            const float e0 = __expf(st0[r] - mn);
            const float e1 = __expf(st1[r] - mn);
            st0[r] = e0; st1[r] = e1;
            sm += e0 + e1;
        }
        sm += __shfl_xor(sm, 32, 64);
        const float alpha = __expf(m_run - mn);
        m_run = mn;
        l_run = l_run * alpha + sm;

        unsigned short* psw = ps[w];
        #pragma unroll
        for (int r = 0; r < 16; r += 2) {
            const int kl = (r & 3) + 8 * (r >> 2) + 4 * half;
            *(unsigned int*)&psw[ln * PSS + kl]      = f2bf2(st0[r], st0[r + 1]);
            *(unsigned int*)&psw[ln * PSS + 32 + kl] = f2bf2(st1[r], st1[r + 1]);
        }
        if (half == 0) alf[w][ln] = alpha;
        #pragma unroll
        for (int r = 0; r < 16; ++r) {
            const int rl = (r & 3) + 8 * (r >> 2) + 4 * half;
            const float ar = alf[w][rl];
            o0[r] *= ar; o1[r] *= ar; o2[r] *= ar; o3[r] *= ar;
        }
        short8 af[4];
        #pragma unroll
        for (int kc = 0; kc < 4; ++kc)
            af[kc] = *(const short8*)&psw[ln * PSS + kc * 16 + half * 8];
        #pragma unroll
        for (int kc = 0; kc < 4; ++kc) {
            const short8 bv0 = *(const short8*)&vt[(ln)      * VTSF + kc * 16 + half * 8];
            const short8 bv1 = *(const short8*)&vt[(32 + ln) * VTSF + kc * 16 + half * 8];
            const short8 bv2 = *(const short8*)&vt[(64 + ln) * VTSF + kc * 16 + half * 8];
            const short8 bv3 = *(const short8*)&vt[(96 + ln) * VTSF + kc * 16 + half * 8];
            o0 = __builtin_amdgcn_mfma_f32_32x32x16_bf16(af[kc], bv0, o0, 0, 0, 0);
            o1 = __builtin_amdgcn_mfma_f32_32x32x16_bf16(af[kc], bv1, o1, 0, 0, 0);
            o2 = __builtin_amdgcn_mfma_f32_32x32x16_bf16(af[kc], bv2, o2, 0, 0, 0);
            o3 = __builtin_amdgcn_mfma_f32_32x32x16_bf16(af[kc], bv3, o3, 0, 0, 0);
        }
    }

    if (half == 0) alf[w][ln] = l_run;
    __builtin_amdgcn_s_waitcnt(0);
    #pragma unroll
    for (int r = 0; r < 16; ++r) {
        const int rl = (r & 3) + 8 * (r >> 2) + 4 * half;
        const float inv = 1.f / alf[w][rl];
        float* orow = out + ((size_t)(wq0 + rl) * NH + h) * HD;
        orow[ln]      = o0[r] * inv;
        orow[32 + ln] = o1[r] * inv;
        orow[64 + ln] = o2[r] * inv;
        orow[96 + ln] = o3[r] * inv;
    }
}

extern "C" void kernel_launch(void* const* d_in, const int* in_sizes, int n_in,
                              void* d_out, int out_size, void* d_ws, size_t ws_size,
                              hipStream_t stream) {
    const float* q = (const float*)d_in[0];
    const float* k = (const float*)d_in[1];
    const float* v = (const float*)d_in[2];
    float* out = (float*)d_out;
    if (ws_size >= (size_t)WS_NEED) {
        unsigned short* kws = (unsigned short*)d_ws;
        unsigned short* vws = kws + KB_ELEMS;
        cvt_kv3<<<256, 256, 0, stream>>>(k, v, kws, vws);
        attn_fwd9<<<256, 512, 0, stream>>>(q, kws, vws, out);
    } else {
        attn_fwd_fb<<<dim3(SEQ / BQ, NH), 256, 0, stream>>>(q, k, v, out);
    }
}

// Round 9
// 146.986 us; speedup vs baseline: 1.0282x; 1.0282x over previous
//
#include <hip/hip_runtime.h>

// Causal GQA attention prefill, fp32 in/out, MFMA 32x32x16 bf16 compute.
// S=2048, H=32, KVH=8 (rep=4), D=128.
// Round 14 on round 13 (72 us, flat): round 13's lag-1 pipeline never
// overlapped -- setprio intrinsics fence the scheduler and the separate
// if(curAct)/if(prevAct) regions are separate basic blocks, so the in-order
// wave issued QK-MFMA, PV-MFMA, then softmax with an empty MFMA pipe.
// This round:
//   1) Steady-state (curAct && prevAct) body is ONE basic block with a
//      hand-distributed interleave: QK(0,1)·PV0·QK(2,3)·PV1·QK(4..7)·mask·
//      exp2(st0)·PV2·pack01·exp2(st1)·PV3·pack23. PV (independent MFMA)
//      fills QK's accumulator-chain stalls and overlaps exp2/cvt runs.
//   2) afp fragments are consumed (PVk) then overwritten (pack) in the same
//      iteration -> lag-1 without extra registers.
//   3) NO setprio anywhere in the loop; only the two correctness
//      sched_barrier(0)s after the inline-asm waitcnt+barrier pairs remain.
// Kept from rounds 12/13: slice-major workspaces (0 conflicts, immediate-
// offset ds_reads), unnormalized softmax (exp2 direct), ones-MFMA row-sum,
// gload_lds width-16 staging, counted-vmcnt depth-2, V triple-buffer
// (ISSUE(it+2) rewrites the buffer PV(it-1) just drained), K double-buffer,
// persistent blocks (grid=256, 17 BK=128 iters), XCD-exact h map.

#define SEQ   2048
#define NH    32
#define NKVH  8
#define HD    128
#define BQ    128
#define BK    128    // staged keys per iteration (2 wave-groups x 64)
#define KSS   136    // fallback kernel K stride
#define VTSF  72     // fallback kernel V stride
#define PSS   72     // fallback ps stride
#define SCALE 0.08838834764831845f
#define QS    (0.08838834764831845f * 1.4426950408889634f)   // SCALE * log2(e)

#define TILE_SH 16384                        // shorts per 128x128 bf16 tile
#define KB_ELEMS (SEQ * NKVH * HD)           // 2,097,152 ushorts
#define WS_NEED  (2u * KB_ELEMS * 2u)        // kws + vws, bytes

typedef __attribute__((ext_vector_type(8)))  short short8;
typedef __attribute__((ext_vector_type(16))) float float16;
typedef __attribute__((ext_vector_type(2)))  unsigned int uint2v;

__device__ __forceinline__ unsigned short f2bf(float f) {
    union { float f; unsigned int i; } x; x.f = f;
    unsigned int r = x.i + 0x7fffu + ((x.i >> 16) & 1u);   // RNE
    return (unsigned short)(r >> 16);
}
__device__ __forceinline__ unsigned int f2bf2(float lo, float hi) {
    return (unsigned int)f2bf(lo) | ((unsigned int)f2bf(hi) << 16);
}
__device__ __forceinline__ unsigned int cvt_pk_bf16(float lo, float hi) {
    unsigned int r;
    asm("v_cvt_pk_bf16_f32 %0, %1, %2" : "=v"(r) : "v"(lo), "v"(hi));
    return r;
}

// direct global->LDS copy, 16 B per lane; LDS dest is wave-uniform base,
// HW adds lane*16; global src is per-lane.
__device__ __forceinline__ void gload_lds16(const unsigned short* g, unsigned short* l) {
    __builtin_amdgcn_global_load_lds(
        (const __attribute__((address_space(1))) void*)g,
        (__attribute__((address_space(3))) void*)l, 16, 0, 0);
}

#if __has_builtin(__builtin_amdgcn_permlane32_swap)
#define PLSWAP(a, b, xout, yout) do { \
    uint2v r_ = __builtin_amdgcn_permlane32_swap((a), (b), false, false); \
    (xout) = r_.x; (yout) = r_.y; } while (0)
#else
#define PLSWAP(a, b, xout, yout) do { \
    unsigned int a_ = (a), b_ = (b); \
    asm volatile("s_nop 1\n\tv_permlane32_swap_b32 %0, %1" : "+v"(a_), "+v"(b_)); \
    (xout) = a_; (yout) = b_; } while (0)
#endif

#define MAKE_AF(dst, sv, b) do { \
    const unsigned int p0_ = cvt_pk_bf16(sv[(b) + 0], sv[(b) + 1]); \
    const unsigned int p1_ = cvt_pk_bf16(sv[(b) + 2], sv[(b) + 3]); \
    const unsigned int p2_ = cvt_pk_bf16(sv[(b) + 4], sv[(b) + 5]); \
    const unsigned int p3_ = cvt_pk_bf16(sv[(b) + 6], sv[(b) + 7]); \
    unsigned int w0_, w1_, w2_, w3_; \
    PLSWAP(p0_, p2_, w0_, w2_); \
    PLSWAP(p1_, p3_, w1_, w3_); \
    union { short8 v; unsigned int u[4]; } uu_; \
    uu_.u[0] = w0_; uu_.u[1] = w1_; uu_.u[2] = w2_; uu_.u[3] = w3_; \
    (dst) = uu_.v; } while (0)

// ---- prep: build slice-major bf16 workspaces ----
// kws[kvh][tile16][gl16][row128] : 8-short unit (gl*128+row)*8 holds
//   K[tile*128+row][d = gl*8 .. gl*8+8) as bf16.
// vws[kvh][tile16][gl16][d128]   : unit (gl*128+d)*8 holds
//   V[key = tile*128+gl*8+e][d], e=0..7 (V^T key-slice at dim d).
__global__ __launch_bounds__(256)
void cvt_kv3(const float* __restrict__ k, const float* __restrict__ v,
             unsigned short* __restrict__ kws, unsigned short* __restrict__ vws)
{
    __shared__ unsigned short tl[128 * 144];
    const int t = threadIdx.x;
    if (blockIdx.x < 128) {                  // ---- K slice-major ----
        const int bid = blockIdx.x;
        const int kvh = bid >> 4, tile = bid & 15;
        unsigned short* dst = kws + (size_t)bid * TILE_SH;
        #pragma unroll
        for (int r = 0; r < 8; ++r) {
            const int gid = r * 256 + t;     // 0..2047
            const int gl = gid >> 7, row = gid & 127;
            const float* src =
                k + ((size_t)(tile * 128 + row) * NKVH + kvh) * HD + gl * 8;
            const float4 a = *(const float4*)(src);
            const float4 b = *(const float4*)(src + 4);
            uint4 o;
            o.x = f2bf2(a.x, a.y); o.y = f2bf2(a.z, a.w);
            o.z = f2bf2(b.x, b.y); o.w = f2bf2(b.z, b.w);
            *(uint4*)(dst + (size_t)gid * 8) = o;
        }
        return;
    }
    // ---- V transpose + slice-major ----
    const int bid = blockIdx.x - 128;
    const int kvh = bid >> 4, tile = bid & 15;
    const int dp  = (t & 63) * 2;
    const int k0q = t >> 6;
    #pragma unroll
    for (int r = 0; r < 32; ++r) {
        const int key = k0q + r * 4;         // 0..127
        const float2 a =
            *(const float2*)(v + ((size_t)(tile * 128 + key) * NKVH + kvh) * HD + dp);
        tl[dp * 144 + key]       = f2bf(a.x);
        tl[(dp + 1) * 144 + key] = f2bf(a.y);
    }
    __syncthreads();
    unsigned short* dst = vws + (size_t)bid * TILE_SH;
    #pragma unroll
    for (int r = 0; r < 8; ++r) {
        const int gid = r * 256 + t;
        const int gl = gid >> 7, d = gid & 127;
        *(uint4*)(dst + (size_t)gid * 8) = *(const uint4*)&tl[d * 144 + gl * 8];
    }
}

// ---- main: persistent 512-thread blocks, 2 q-tiles each, 17 iters total ----
__global__ __launch_bounds__(512, 1)
void attn_fwd10(const float* __restrict__ q,
                const unsigned short* __restrict__ kws,
                const unsigned short* __restrict__ vws,
                float* __restrict__ out)
{
    // K double-buffer (2x32KB) + V triple-buffer (3x32KB) = 163840 B (max).
    // epilogue: obuf (64KB) aliases K region; Sl aliases V region (dead).
    __shared__ __align__(16) unsigned char smem[163840];
    unsigned short* const ks0 = (unsigned short*)smem;
    unsigned short* const ks1 = (unsigned short*)(smem + 32768);
    unsigned short* const vb0 = (unsigned short*)(smem + 65536);
    unsigned short* const vb1 = (unsigned short*)(smem + 98304);
    unsigned short* const vb2 = (unsigned short*)(smem + 131072);
    float*          const obuf = (float*)smem;                 // 64 KB
    float*          const Slp  = (float*)(smem + 65536);       // 1 KB, epilogue only

    const int t    = threadIdx.x;          // 0..511
    const int w    = t >> 6;               // wave 0..7
    const int lane = t & 63;
    const int ln   = lane & 31;
    const int half = lane >> 5;
    const int g    = w >> 2;               // key-group 0/1
    const int w3   = w & 3;                // q-subtile 0..3

    // XCD-exact mapping: blocks with bid%8==x share kvh==x on XCD x.
    const int bid = blockIdx.x;            // 0..255
    const int h   = (bid & 7) * 4 + ((bid >> 3) & 3);
    const int px  = bid >> 5;              // 0..7
    const int kvh = h >> 2;

    // slice-major per-lane LDS read bases (shorts); all reads are
    // base + compile-time immediate offsets.
    const int kofs = half * 1024 + (g * 64 + ln) * 8;   // K: [gl][row]
    const int vofs = (g * 8 + half) * 1024 + ln * 8;    // V: [gl][d]

    // linear staging sources: thread t covers bytes t*16 + j*8192 of tile.
    const unsigned short* const kgp = kws + (size_t)(kvh * 16) * TILE_SH + t * 8;
    const unsigned short* const vgp = vws + (size_t)(kvh * 16) * TILE_SH + t * 8;
    const int wofs = w * 512;              // wave-uniform LDS offset (shorts)

    // all-ones bf16 B fragment for the l row-sum MFMA
    short8 onesv;
    {
        union { short8 v; unsigned int u[4]; } uo;
        uo.u[0] = uo.u[1] = uo.u[2] = uo.u[3] = 0x3F803F80u;
        onesv = uo.v;
    }

#define ISSUE(tix, kb_, vb_) do { \
    const unsigned short* kg_ = kgp + (size_t)(tix) * TILE_SH; \
    const unsigned short* vg_ = vgp + (size_t)(tix) * TILE_SH; \
    gload_lds16(kg_,         (kb_) + wofs); \
    gload_lds16(kg_ +  4096, (kb_) + wofs + 4096); \
    gload_lds16(kg_ +  8192, (kb_) + wofs + 8192); \
    gload_lds16(kg_ + 12288, (kb_) + wofs + 12288); \
    gload_lds16(vg_,         (vb_) + wofs); \
    gload_lds16(vg_ +  4096, (vb_) + wofs + 4096); \
    gload_lds16(vg_ +  8192, (vb_) + wofs + 8192); \
    gload_lds16(vg_ + 12288, (vb_) + wofs + 12288); \
} while (0)

// body pieces (textual macros; expanded where ksc/vpc/st0/st1/... in scope)
#define M_QK(k0) do { \
    const short8 a0_ = *(const short8*)&ksc[(k0) * 2048]; \
    const short8 a1_ = *(const short8*)&ksc[(k0) * 2048 + 256]; \
    st0 = __builtin_amdgcn_mfma_f32_32x32x16_bf16(a0_, qf[(k0)], (k0) ? st0 : z16, 0, 0, 0); \
    st1 = __builtin_amdgcn_mfma_f32_32x32x16_bf16(a1_, qf[(k0)], (k0) ? st1 : z16, 0, 0, 0); \
} while (0)

#define M_PV(afx, kc) do { \
    const short8 bv0_ = *(const short8*)&vpc[(kc) * 2048]; \
    const short8 bv1_ = *(const short8*)&vpc[(kc) * 2048 + 256]; \
    const short8 bv2_ = *(const short8*)&vpc[(kc) * 2048 + 512]; \
    const short8 bv3_ = *(const short8*)&vpc[(kc) * 2048 + 768]; \
    o0 = __builtin_amdgcn_mfma_f32_32x32x16_bf16(afx, bv0_, o0, 0, 0, 0); \
    o1 = __builtin_amdgcn_mfma_f32_32x32x16_bf16(afx, bv1_, o1, 0, 0, 0); \
    o2 = __builtin_amdgcn_mfma_f32_32x32x16_bf16(afx, bv2_, o2, 0, 0, 0); \
    o3 = __builtin_amdgcn_mfma_f32_32x32x16_bf16(afx, bv3_, o3, 0, 0, 0); \
    lacc = __builtin_amdgcn_mfma_f32_32x32x16_bf16(afx, onesv, lacc, 0, 0, 0); \
} while (0)

#define M_MASK do { \
    if ((j0g + 63) > wq0) { \
        _Pragma("unroll") \
        for (int r = 0; r < 16; ++r) { \
            const int kl = (r & 3) + 8 * (r >> 2) + 4 * half; \
            if (j0g + kl > qrow)      st0[r] = -1e30f; \
            if (j0g + 32 + kl > qrow) st1[r] = -1e30f; \
        } \
    } \
} while (0)

#define M_EXP0 do { _Pragma("unroll") for (int r = 0; r < 16; ++r) st0[r] = exp2f(st0[r]); } while (0)
#define M_EXP1 do { _Pragma("unroll") for (int r = 0; r < 16; ++r) st1[r] = exp2f(st1[r]); } while (0)
#define M_PACK01 do { MAKE_AF(afp0, st0, 0); MAKE_AF(afp1, st0, 8); } while (0)
#define M_PACK23 do { MAKE_AF(afp2, st1, 0); MAKE_AF(afp3, st1, 8); } while (0)

    for (int ph = 0; ph < 2; ++ph) {
        const int bx    = ph ? (15 - px) : px;
        const int q0    = bx * BQ;
        const int wq0   = q0 + w3 * 32;
        const int qrow  = wq0 + ln;
        const int wqmax = wq0 + 31;
        const int nit   = bx + 1;          // BK=128 iterations

        // ---- Q fragments, pre-scaled by SCALE*log2(e) ----
        short8 qf[8];
        {
            const float* qr = q + ((size_t)qrow * NH + h) * HD;
            #pragma unroll
            for (int k0 = 0; k0 < 8; ++k0) {
                const float* p4 = qr + k0 * 16 + half * 8;
                const float4 a = *(const float4*)(p4);
                const float4 b = *(const float4*)(p4 + 4);
                union { short8 v; unsigned int u[4]; } uu;
                uu.u[0] = f2bf2(a.x * QS, a.y * QS);
                uu.u[1] = f2bf2(a.z * QS, a.w * QS);
                uu.u[2] = f2bf2(b.x * QS, b.y * QS);
                uu.u[3] = f2bf2(b.z * QS, b.w * QS);
                qf[k0] = uu.v;
            }
        }

        float16 o0, o1, o2, o3, lacc, z16;
        #pragma unroll
        for (int i = 0; i < 16; ++i) {
            o0[i] = 0.f; o1[i] = 0.f; o2[i] = 0.f; o3[i] = 0.f;
            lacc[i] = 0.f; z16[i] = 0.f;
        }

        short8 afp0 = onesv, afp1 = onesv, afp2 = onesv, afp3 = onesv;
        bool prevAct = false;

        // V buffer rotation: tile t lives in buf t%3.
        unsigned short* vA = vb0;          // holds tile it   (current)
        unsigned short* vB = vb1;          // holds tile it+1 (next)
        unsigned short* vC = vb2;          // holds tile it-1 (prev / write target)

        ISSUE(0, ks0, vb0);
        if (nit > 1) ISSUE(1, ks1, vb1);

        for (int it = 0; it < nit; ++it) {
            const int cur = it & 1;
            const unsigned short* ksc = (cur ? ks1 : ks0) + kofs;
            const unsigned short* vpc = vC + vofs;   // tile it-1's V

            // tile it complete; tile it+1's 8 loads may stay in flight
            if (it + 1 < nit) asm volatile("s_waitcnt vmcnt(8)" ::: "memory");
            else              asm volatile("s_waitcnt vmcnt(0)" ::: "memory");
            __builtin_amdgcn_s_barrier();
            __builtin_amdgcn_sched_barrier(0);

            const int j0g = it * BK + g * 64;   // this wave-group's key base
            const bool curAct = (j0g <= wqmax);

            float16 st0, st1;
            if (curAct & prevAct) {
                // ---- steady state: ONE basic block, hand-interleaved ----
                M_QK(0); M_QK(1);
                M_PV(afp0, 0);
                M_QK(2); M_QK(3);
                M_PV(afp1, 1);
                M_QK(4); M_QK(5); M_QK(6); M_QK(7);
                M_MASK;
                M_EXP0;
                M_PV(afp2, 2);
                M_PACK01;
                M_EXP1;
                M_PV(afp3, 3);
                M_PACK23;
            } else if (curAct) {
                // first active iteration: no previous P
                M_QK(0); M_QK(1); M_QK(2); M_QK(3);
                M_QK(4); M_QK(5); M_QK(6); M_QK(7);
                M_MASK;
                M_EXP0; M_PACK01;
                M_EXP1; M_PACK23;
            } else if (prevAct) {
                // drain-in-loop: PV of the last active tile
                M_PV(afp0, 0); M_PV(afp1, 1); M_PV(afp2, 2); M_PV(afp3, 3);
            }

            // all LDS reads of this window's buffers complete before restage
            asm volatile("s_waitcnt lgkmcnt(0)" ::: "memory");
            __builtin_amdgcn_s_barrier();
            __builtin_amdgcn_sched_barrier(0);
            // K(it+2) -> ks[cur] (just-read K buffer); V(it+2) -> vC
            // ((it+2) == (it-1) mod 3: the buffer PV just drained).
            if (it + 2 < nit) ISSUE(it + 2, cur ? ks1 : ks0, vC);

            // rotate V buffers: prev <- cur, cur <- next, next <- old prev
            unsigned short* tmp = vC; vC = vA; vA = vB; vB = tmp;
            prevAct = curAct;
        }

        // ---- drain: PV of the final tile (vC holds tile nit-1 after rotation)
        if (prevAct) {
            const unsigned short* vpc = vC + vofs;
            M_PV(afp0, 0); M_PV(afp1, 1); M_PV(afp2, 2); M_PV(afp3, 3);
        }

        // ---- epilogue: merge key-group partials, write out ----
        __syncthreads();                   // all compute + LDS reads done
        if (ln == 0) {
            #pragma unroll
            for (int r = 0; r < 16; ++r)
                Slp[((g * 4 + w3) * 32) + ((r & 3) + 8 * (r >> 2) + 4 * half)] = lacc[r];
        }
        if (g == 1) {
            #pragma unroll
            for (int r = 0; r < 16; ++r) {
                const int rl = (r & 3) + 8 * (r >> 2) + 4 * half;
                float* ob = &obuf[(size_t)(w3 * 32 + rl) * 128];
                ob[ln]      = o0[r];
                ob[32 + ln] = o1[r];
                ob[64 + ln] = o2[r];
                ob[96 + ln] = o3[r];
            }
        }
        __syncthreads();
        if (g == 0) {
            #pragma unroll
            for (int r = 0; r < 16; ++r) {
                const int rl = (r & 3) + 8 * (r >> 2) + 4 * half;
                const float inv = 1.f / (Slp[(w3 * 32) + rl] + Slp[((4 + w3) * 32) + rl]);
                const float* ob = &obuf[(size_t)(w3 * 32 + rl) * 128];
                float* orow = out + ((size_t)(wq0 + rl) * NH + h) * HD;
                orow[ln]      = (o0[r] + ob[ln])      * inv;
                orow[32 + ln] = (o1[r] + ob[32 + ln]) * inv;
                orow[64 + ln] = (o2[r] + ob[64 + ln]) * inv;
                orow[96 + ln] = (o3[r] + ob[96 + ln]) * inv;
            }
        }
        __syncthreads();   // obuf/Sl reads done before next phase restages pool
    }
#undef M_QK
#undef M_PV
#undef M_MASK
#undef M_EXP0
#undef M_EXP1
#undef M_PACK01
#undef M_PACK23
#undef ISSUE
}

// ---- fallback (round-4 kernel, no workspace needed) ----
__global__ __launch_bounds__(256, 2)
void attn_fwd_fb(const float* __restrict__ q,
                 const float* __restrict__ k,
                 const float* __restrict__ v,
                 float* __restrict__ out)
{
    __shared__ unsigned short ks[64 * KSS];
    __shared__ unsigned short vt[HD * VTSF];
    __shared__ unsigned short ps[4][32 * PSS];
    __shared__ float          alf[4][32];

    const int t    = threadIdx.x;
    const int w    = t >> 6;
    const int lane = t & 63;
    const int ln   = lane & 31;
    const int half = lane >> 5;
    const int h    = blockIdx.y;
    const int kvh  = h >> 2;
    const int q0   = blockIdx.x * BQ;
    const int wq0  = q0 + w * 32;
    const int qrow = wq0 + ln;

    short8 qf[8];
    {
        const float* qr = q + ((size_t)qrow * NH + h) * HD;
        #pragma unroll
        for (int k0 = 0; k0 < 8; ++k0) {
            const float* p4 = qr + k0 * 16 + half * 8;
            const float4 a = *(const float4*)(p4);
            const float4 b = *(const float4*)(p4 + 4);
            union { short8 v; unsigned int u[4]; } uu;
            uu.u[0] = f2bf2(a.x, a.y);
            uu.u[1] = f2bf2(a.z, a.w);
            uu.u[2] = f2bf2(b.x, b.y);
            uu.u[3] = f2bf2(b.z, b.w);
            qf[k0] = uu.v;
        }
    }

    float16 o0, o1, o2, o3;
    #pragma unroll
    for (int i = 0; i < 16; ++i) { o0[i] = 0.f; o1[i] = 0.f; o2[i] = 0.f; o3[i] = 0.f; }
    float m_run = -1e30f, l_run = 0.f;
    const int ntiles = (q0 + BQ) / 64;
    const int wqmax  = wq0 + 31;

    for (int it = 0; it < ntiles; ++it) {
        const int j0 = it * 64;
        __syncthreads();
        {
            const int key = t >> 2;
            const int db  = (t & 3) * 4;
            const float* kr = k + ((size_t)(j0 + key) * NKVH + kvh) * HD;
            #pragma unroll
            for (int r2 = 0; r2 < 8; ++r2) {
                const int d = db + r2 * 16;
                const float4 a = *(const float4*)(kr + d);
                *(unsigned int*)&ks[key * KSS + d]     = f2bf2(a.x, a.y);
                *(unsigned int*)&ks[key * KSS + d + 2] = f2bf2(a.z, a.w);
            }
        }
        {
            const int kp = (t & 31) * 2;
            const int db = (t >> 5) * 4;
            const float* vr0 = v + ((size_t)(j0 + kp) * NKVH + kvh) * HD;
            const float* vr1 = vr0 + NKVH * HD;
            #pragma unroll
            for (int r2 = 0; r2 < 4; ++r2) {
                const int d = db + r2 * 32;
                const float4 a = *(const float4*)(vr0 + d);
                const float4 b = *(const float4*)(vr1 + d);
                *(unsigned int*)&vt[(d + 0) * VTSF + kp] = f2bf2(a.x, b.x);
                *(unsigned int*)&vt[(d + 1) * VTSF + kp] = f2bf2(a.y, b.y);
                *(unsigned int*)&vt[(d + 2) * VTSF + kp] = f2bf2(a.z, b.z);
                *(unsigned int*)&vt[(d + 3) * VTSF + kp] = f2bf2(a.w, b.w);
            }
        }
        __syncthreads();
        if (j0 > wqmax) continue;

        float16 st0, st1;
        #pragma unroll
        for (int i = 0; i < 16; ++i) { st0[i] = 0.f; st1[i] = 0.f; }
        #pragma unroll
        for (int k0 = 0; k0 < 8; ++k0) {
            const short8 a0 = *(const short8*)&ks[ln * KSS + k0 * 16 + half * 8];
            const short8 a1 = *(const short8*)&ks[(32 + ln) * KSS + k0 * 16 + half * 8];
            st0 = __builtin_amdgcn_mfma_f32_32x32x16_bf16(a0, qf[k0], st0, 0, 0, 0);
            st1 = __builtin_amdgcn_mfma_f32_32x32x16_bf16(a1, qf[k0], st1, 0, 0, 0);
        }
        const bool need_mask = (j0 + 63) > wq0;
        float mt = -1e30f;
        #pragma unroll
        for (int r = 0; r < 16; ++r) {
            const int kl = (r & 3) + 8 * (r >> 2) + 4 * half;
            float a0 = st0[r] * SCALE;
            float a1 = st1[r] * SCALE;
            if (need_mask) {
                if (j0 + kl > qrow)      a0 = -1e30f;
                if (j0 + 32 + kl > qrow) a1 = -1e30f;
            }
            st0[r] = a0; st1[r] = a1;
            mt = fmaxf(mt, fmaxf(a0, a1));
        }
        mt = fmaxf(mt, __shfl_xor(mt, 32, 64));
        const float mn = fmaxf(m_run, mt);
        float sm = 0.f;
        #pragma unroll
        for (int r = 0; r < 16; ++r) {
            const float e0 = __expf(st0[r] - mn);
            const float e1 = __expf(st1[r] - mn);
            st0[r] = e0; st1[r] = e1;
            sm += e0 + e1;
        }
        sm += __shfl_xor(sm, 32, 64);
        const float alpha = __expf(m_run - mn);
        m_run = mn;
        l_run = l_run * alpha + sm;

        unsigned short* psw = ps[w];
        #pragma unroll
        for (int r = 0; r < 16; r += 2) {
            const int kl = (r & 3) + 8 * (r >> 2) + 4 * half;
            *(unsigned int*)&psw[ln * PSS + kl]      = f2bf2(st0[r], st0[r + 1]);
            *(unsigned int*)&psw[ln * PSS + 32 + kl] = f2bf2(st1[r], st1[r + 1]);
        }
        if (half == 0) alf[w][ln] = alpha;
        #pragma unroll
        for (int r = 0; r < 16; ++r) {
            const int rl = (r & 3) + 8 * (r >> 2) + 4 * half;
            const float ar = alf[w][rl];
            o0[r] *= ar; o1[r] *= ar; o2[r] *= ar; o3[r] *= ar;
        }
        short8 af[4];
        #pragma unroll
        for (int kc = 0; kc < 4; ++kc)
            af[kc] = *(const short8*)&psw[ln * PSS + kc * 16 + half * 8];
        #pragma unroll
        for (int kc = 0; kc < 4; ++kc) {
            const short8 bv0 = *(const short8*)&vt[(ln)      * VTSF + kc * 16 + half * 8];
            const short8 bv1 = *(const short8*)&vt[(32 + ln) * VTSF + kc * 16 + half * 8];
            const short8 bv2 = *(const short8*)&vt[(64 + ln) * VTSF + kc * 16 + half * 8];
            const short8 bv3 = *(const short8*)&vt[(96 + ln) * VTSF + kc * 16 + half * 8];
            o0 = __builtin_amdgcn_mfma_f32_32x32x16_bf16(af[kc], bv0, o0, 0, 0, 0);
            o1 = __builtin_amdgcn_mfma_f32_32x32x16_bf16(af[kc], bv1, o1, 0, 0, 0);
            o2 = __builtin_amdgcn_mfma_f32_32x32x16_bf16(af[kc], bv2, o2, 0, 0, 0);
            o3 = __builtin_amdgcn_mfma_f32_32x32x16_bf16(af[kc], bv3, o3, 0, 0, 0);
        }
    }

    if (half == 0) alf[w][ln] = l_run;
    __builtin_amdgcn_s_waitcnt(0);
    #pragma unroll
    for (int r = 0; r < 16; ++r) {
        const int rl = (r & 3) + 8 * (r >> 2) + 4 * half;
        const float inv = 1.f / alf[w][rl];
        float* orow = out + ((size_t)(wq0 + rl) * NH + h) * HD;
        orow[ln]      = o0[r] * inv;
        orow[32 + ln] = o1[r] * inv;
        orow[64 + ln] = o2[r] * inv;
        orow[96 + ln] = o3[r] * inv;
    }
}

extern "C" void kernel_launch(void* const* d_in, const int* in_sizes, int n_in,
                              void* d_out, int out_size, void* d_ws, size_t ws_size,
                              hipStream_t stream) {
    const float* q = (const float*)d_in[0];
    const float* k = (const float*)d_in[1];
    const float* v = (const float*)d_in[2];
    float* out = (float*)d_out;
    if (ws_size >= (size_t)WS_NEED) {
        unsigned short* kws = (unsigned short*)d_ws;
        unsigned short* vws = kws + KB_ELEMS;
        cvt_kv3<<<256, 256, 0, stream>>>(k, v, kws, vws);
        attn_fwd10<<<256, 512, 0, stream>>>(q, kws, vws, out);
    } else {
        attn_fwd_fb<<<dim3(SEQ / BQ, NH), 256, 0, stream>>>(q, k, v, out);
    }
}